// Round 4
// baseline (316.492 us; speedup 1.0000x reference)
//
#include <hip/hip_runtime.h>

// LSTM B=8192,T=256,I=1,H=50 via MFMA, operand-swapped layout.
// Per block: 16 batches, 4 waves. Per step: D[208x16] = W[208x64] x h[64x16],
// rows = unit*4 + gate (52 units: 50 real + x-col + bias-col), cols = batches.
// C/D layout (col=lane&15, row=quad*4+reg) => each lane's 4 acc regs are the
// 4 gates (i,f,g,o) of one (batch=lane&15, unit=4T+quad) -- elementwise runs
// in-register, no gates LDS round-trip, ONE barrier/step (h double-buffered).
// h carried as bf16 hi+lo planes; 3-product MFMA ~ fp32 (verified R3).

#define NTH 256
#define TST 256
#define MB 16
#define NBLK 512
#define HR 72            // h row stride in shorts (16B-aligned frag reads)
#define HSZ (MB * HR)    // 1152

typedef __attribute__((ext_vector_type(8))) short short8;
typedef __attribute__((ext_vector_type(4))) float float4v;

__device__ __forceinline__ unsigned short bfhi(float v) {
    return (unsigned short)(__float_as_uint(v) >> 16);  // truncate; lo catches rest
}
__device__ __forceinline__ float bfup(unsigned short u) {
    return __uint_as_float(((unsigned int)u) << 16);
}
__device__ __forceinline__ float sigm(float v) {
    return __builtin_amdgcn_rcpf(1.0f + __expf(-v));
}
__device__ __forceinline__ float tanh_fast(float v) {
    float e = __expf(2.0f * v);
    return 1.0f - 2.0f * __builtin_amdgcn_rcpf(e + 1.0f);
}

__global__ __launch_bounds__(NTH) void lstm_mfma(
    const float* __restrict__ x,      // [8192][256]
    const float* __restrict__ W_ih,   // [200]
    const float* __restrict__ W_hh,   // [200][50]
    const float* __restrict__ b_ih,   // [200]
    const float* __restrict__ b_hh,   // [200]
    const float* __restrict__ W_lin,  // [50]
    const float* __restrict__ b_lin,  // [1]
    float* __restrict__ out)          // [8192]
{
    __shared__ __align__(16) unsigned short Hhi[2 * HSZ];  // [buf][b*HR + k]
    __shared__ __align__(16) unsigned short Hlo[2 * HSZ];
    __shared__ __align__(16) float xs[64 * 17];            // x chunk [t&63][b]

    const int tid  = threadIdx.x;
    const int wv   = tid >> 6;
    const int ln   = tid & 63;
    const int lrow = ln & 15;   // A-row index / B-col (batch) / D-col (batch)
    const int quad = ln >> 4;
    const int bbase = (int)blockIdx.x * MB;

    // ---- W-operand ("A") fragments: row m = lrow within tile T = wv + 4s.
    // Global row gr = T*16 + m -> unit j = gr>>2, gate g = gr&3, W row = g*50+j.
    // k = q2*32 + quad*8 + i; k=50 -> W_ih, k=51 -> bias, else W_hh[.,k].
    // Tiles T>12 or j>=50 rows are zero (pad); one-time global reads, L2-cached.
    short8 wh[4][2], wl[4][2];
    #pragma unroll
    for (int s = 0; s < 4; ++s) {
        const int T  = wv + 4 * s;
        const int gr = T * 16 + lrow;
        const int j  = gr >> 2, g = gr & 3;
        const int row = g * 50 + j;   // only dereferenced when j < 50
        #pragma unroll
        for (int q2 = 0; q2 < 2; ++q2) {
            short8 h8, l8;
            #pragma unroll
            for (int i = 0; i < 8; ++i) {
                const int k = q2 * 32 + quad * 8 + i;
                float V = 0.0f;
                if (j < 50) {
                    if (k < 50)       V = W_hh[row * 50 + k];
                    else if (k == 50) V = W_ih[row];
                    else if (k == 51) V = b_ih[row] + b_hh[row];
                }
                unsigned short hb = bfhi(V);
                h8[i] = (short)hb;
                l8[i] = (short)bfhi(V - bfup(hb));
            }
            wh[s][q2] = h8;
            wl[s][q2] = l8;
        }
    }

    // ---- init h planes to zero; slots k=50 (x(0)) and k=51 (1.0, BOTH bufs)
    for (int i = tid; i < HSZ; i += NTH) {  // 2*HSZ shorts = HSZ dwords per plane
        ((unsigned int*)Hhi)[i] = 0u;
        ((unsigned int*)Hlo)[i] = 0u;
    }
    __syncthreads();
    if (tid < MB) {
        float xv = x[(bbase + tid) * TST + 0];
        unsigned short xh = bfhi(xv);
        Hhi[0 * HSZ + tid * HR + 50] = xh;
        Hlo[0 * HSZ + tid * HR + 50] = bfhi(xv - bfup(xh));
        Hhi[0 * HSZ + tid * HR + 51] = 0x3F80;  // bf16(1.0), constant: never rewritten
        Hhi[1 * HSZ + tid * HR + 51] = 0x3F80;
    }
    {   // stage xs chunk 0: x[0..63]
        const int b = tid & 15, i0 = (tid >> 4) * 4;
        const float4 v4 = *(const float4*)&x[(bbase + b) * TST + i0];
        xs[(i0 + 0) * 17 + b] = v4.x;
        xs[(i0 + 1) * 17 + b] = v4.y;
        xs[(i0 + 2) * 17 + b] = v4.z;
        xs[(i0 + 3) * 17 + b] = v4.w;
    }
    float cst[4] = {0.f, 0.f, 0.f, 0.f};
    __syncthreads();

    for (int t = 0; t < TST; ++t) {
        const int buf  = (t & 1) * HSZ;
        const int nbuf = HSZ - buf;

        // restage next 64 x values at t=63,127,191 (slot0 rewrite is same-value)
        if (((t & 63) == 63) && t != 255) {
            const int b = tid & 15, i0 = (tid >> 4) * 4;
            const float4 v4 = *(const float4*)&x[(bbase + b) * TST + (t + 1) + i0];
            xs[(i0 + 0) * 17 + b] = v4.x;
            xs[(i0 + 1) * 17 + b] = v4.y;
            xs[(i0 + 2) * 17 + b] = v4.z;
            xs[(i0 + 3) * 17 + b] = v4.w;
        }

        // ---- h-operand ("B") frags: lane&15 = batch, k = quad*8+i (+32)
        const int ha = buf + lrow * HR + quad * 8;
        const short8 bh0 = *(const short8*)&Hhi[ha];
        const short8 bh1 = *(const short8*)&Hhi[ha + 32];
        const short8 bl0 = *(const short8*)&Hlo[ha];
        const short8 bl1 = *(const short8*)&Hlo[ha + 32];

        #pragma unroll
        for (int s = 0; s < 4; ++s) {
            if (s == 3 && wv != 0) break;   // 13 tiles: waves get 4/3/3/3
            float4v acc = {0.f, 0.f, 0.f, 0.f};
            acc = __builtin_amdgcn_mfma_f32_16x16x32_bf16(wh[s][0], bh0, acc, 0, 0, 0);
            acc = __builtin_amdgcn_mfma_f32_16x16x32_bf16(wh[s][1], bh1, acc, 0, 0, 0);
            acc = __builtin_amdgcn_mfma_f32_16x16x32_bf16(wl[s][0], bh0, acc, 0, 0, 0);
            acc = __builtin_amdgcn_mfma_f32_16x16x32_bf16(wl[s][1], bh1, acc, 0, 0, 0);
            acc = __builtin_amdgcn_mfma_f32_16x16x32_bf16(wh[s][0], bl0, acc, 0, 0, 0);
            acc = __builtin_amdgcn_mfma_f32_16x16x32_bf16(wh[s][1], bl1, acc, 0, 0, 0);

            // lane = (batch lrow, unit j = 4T + quad); regs = gates i,f,g,o
            float i_ = sigm(acc[0]);
            float f_ = sigm(acc[1]);
            float g_ = tanh_fast(acc[2]);
            float o_ = sigm(acc[3]);
            float cn = f_ * cst[s] + i_ * g_;
            cst[s] = cn;
            float hn = o_ * tanh_fast(cn);

            const int T = wv + 4 * s;
            bool wr = true;
            if (T == 12) {                      // wave 0 only: units 48..51
                if (quad == 2)      hn = xs[((t + 1) & 63) * 17 + lrow];  // k=50: x(t+1)
                else if (quad == 3) wr = false;                           // k=51: keep 1.0
            }
            if (wr) {
                const int j = T * 4 + quad;
                unsigned short hh = bfhi(hn);
                Hhi[nbuf + lrow * HR + j] = hh;
                Hlo[nbuf + lrow * HR + j] = bfhi(hn - bfup(hh));
            }
        }
        __syncthreads();   // writes to nbuf visible before next step's reads
    }

    // ---- epilogue: final h is in buf 0 (writes at t=255 went to nbuf=0)
    if (tid < MB) {
        float s = b_lin[0];
        #pragma unroll 10
        for (int k = 0; k < 50; ++k) {
            float hk = bfup(Hhi[tid * HR + k]) + bfup(Hlo[tid * HR + k]);
            s += hk * W_lin[k];
        }
        out[bbase + tid] = s;
    }
}

extern "C" void kernel_launch(void* const* d_in, const int* in_sizes, int n_in,
                              void* d_out, int out_size, void* d_ws, size_t ws_size,
                              hipStream_t stream) {
    const float* x     = (const float*)d_in[0];
    const float* W_ih  = (const float*)d_in[1];
    const float* W_hh  = (const float*)d_in[2];
    const float* b_ih  = (const float*)d_in[3];
    const float* b_hh  = (const float*)d_in[4];
    const float* W_lin = (const float*)d_in[5];
    const float* b_lin = (const float*)d_in[6];
    float* out = (float*)d_out;

    lstm_mfma<<<dim3(NBLK), dim3(NTH), 0, stream>>>(
        x, W_ih, W_hh, b_ih, b_hh, W_lin, b_lin, out);
}